// Round 5
// baseline (110.122 us; speedup 1.0000x reference)
//
#include <hip/hip_runtime.h>

typedef _Float16 f16x8 __attribute__((ext_vector_type(8)));
typedef _Float16 f16x4 __attribute__((ext_vector_type(4)));
typedef float    f32x4 __attribute__((ext_vector_type(4)));

constexpr int NTOK   = 1568;   // T*H*W = 8*14*14
constexpr int NHEADS = 8;
constexpr int NCH    = 512;
constexpr int NTILE  = 13;     // 128-token K/V tiles, last zero-padded
constexpr int TILE_BYTES = 32768;   // 16KB K-image + 16KB V-image

union v8u { f16x8 v8; f16x4 v4[2]; };

// ---- pre-pass: build per-(bh,tile) 32KB LDS images ----
// K image: [tok 0..127][128B]  byte col = (2d) ^ ((tok&7)<<4), value x*(1/8), zero-padded
// V image: [d 0..63][256B]     byte col = (2*tok_local) ^ ((d&7)<<4), value x, zero-padded
__global__ __launch_bounds__(256)
void prep_kernel(const float* __restrict__ x, char* __restrict__ img)
{
    const int bh = blockIdx.x, tile = blockIdx.y;
    const int b = bh >> 3, h = bh & 7;
    const int t = threadIdx.x;
    const int d = t & 63, q = t >> 6;       // token quarter (32 tokens), wave-uniform
    const int n0 = tile * 128 + q * 32;
    const bool valid = n0 < NTOK;           // 1568 % 32 == 0: all-or-nothing per quarter

    __shared__ __align__(16) char kimg[128 * 144];   // swizzled K image rows, pitch 144B

    char* tb = img + ((size_t)bh * NTILE + tile) * TILE_BYTES;

    float v[32];
    const float* src = x + ((size_t)b * NCH + d * NHEADS + h) * NTOK + n0;
#pragma unroll
    for (int i = 0; i < 8; ++i) {
        f32x4 f = {0.f, 0.f, 0.f, 0.f};
        if (valid) f = *(const f32x4*)(src + 4 * i);
        v[4*i+0] = f[0]; v[4*i+1] = f[1]; v[4*i+2] = f[2]; v[4*i+3] = f[3];
    }

    // V image rows (d fixed per thread): 4 x 16B swizzled-slot stores
    const int swzd = (d & 7) << 4;
#pragma unroll
    for (int m = 0; m < 4; ++m) {
        f16x8 o;
#pragma unroll
        for (int j = 0; j < 8; ++j) o[j] = (_Float16)v[8*m + j];
        *(f16x8*)(tb + 16384 + d * 256 + ((q*64 + m*16) ^ swzd)) = o;
    }

    // K image into LDS (scalar f16 writes: whole wave same token -> 2-way banks, free)
#pragma unroll
    for (int j = 0; j < 32; ++j) {
        const int tok = q * 32 + j;
        *(_Float16*)&kimg[tok * 144 + ((2*d) ^ ((j & 7) << 4))] = (_Float16)(v[j] * 0.125f);
    }
    __syncthreads();
    {   // linear copy LDS image -> global image
        const int tok = t >> 1, half = t & 1;
#pragma unroll
        for (int m = 0; m < 4; ++m) {
            const int off = half * 64 + m * 16;
            *(f16x8*)(tb + tok * 128 + off) = *(const f16x8*)&kimg[tok * 144 + off];
        }
    }
}

// ---- per-tile: S^T = K_quarter (Q/64)^T (2 q-subgroups), p=exp(s) lane-local, O^T += V^T P^T ----
template<bool LAST>
__device__ __forceinline__ void tile_compute(const char* __restrict__ buf,
    int kw, int l15, int grp, int swz,
    const f16x8 (&aq)[2][2], f32x4 (&oacc)[2][4], float (&lsum)[2])
{
    f16x8 kf[2][2];
#pragma unroll
    for (int cb = 0; cb < 2; ++cb) {
        const char* krow = buf + (size_t)(kw*32 + cb*16 + l15) * 128;   // row&7 == l15&7
        kf[cb][0] = *(const f16x8*)(krow + ((grp*16) ^ swz));
        kf[cb][1] = *(const f16x8*)(krow + ((64 + grp*16) ^ swz));
    }
    const f32x4 z4 = {0.f, 0.f, 0.f, 0.f};
    f32x4 sacc[2][2] = {{z4, z4}, {z4, z4}};
#pragma unroll
    for (int sub = 0; sub < 2; ++sub)
#pragma unroll
        for (int cb = 0; cb < 2; ++cb)
#pragma unroll
            for (int ks = 0; ks < 2; ++ks)
                sacc[sub][cb] = __builtin_amdgcn_mfma_f32_16x16x32_f16(kf[cb][ks], aq[sub][ks], sacc[sub][cb], 0, 0, 0);

    // lane-local softmax numerator; lsum from ROUNDED p (num/den rounding cancels)
    f16x8 bp[2];
#pragma unroll
    for (int sub = 0; sub < 2; ++sub)
#pragma unroll
        for (int cb = 0; cb < 2; ++cb)
#pragma unroll
            for (int r = 0; r < 4; ++r) {
                const _Float16 ph = (_Float16)__expf(sacc[sub][cb][r]);
                bp[sub][cb*4 + r] = ph;                  // token 16*cb + 4*grp + r (quarter-local)
                if (!LAST || kw == 0) lsum[sub] += (float)ph;   // last tile: only quarter 0 valid
            }

    const char* vimg = buf + 16384;
#pragma unroll
    for (int db = 0; db < 4; ++db) {
        const char* vrow = vimg + (size_t)(db*16 + l15) * 256;          // row&7 == l15&7
        v8u av;   // A-frag slot (grp,j): token kw*32 + 16*(j>>2) + 4*grp + (j&3)
        av.v4[0] = *(const f16x4*)(vrow + ((kw*64 + grp*8) ^ swz));
        av.v4[1] = *(const f16x4*)(vrow + ((kw*64 + 32 + grp*8) ^ swz));
#pragma unroll
        for (int sub = 0; sub < 2; ++sub)
            oacc[sub][db] = __builtin_amdgcn_mfma_f32_16x16x32_f16(av.v8, bp[sub], oacc[sub][db], 0, 0, 0);
    }
}

__global__ __launch_bounds__(512, 4)
void attn_fwd(const char* __restrict__ img, float* __restrict__ out)
{
    // XCD-aware bijective remap (800 = 8*100): 4 bh per XCD -> images L2-resident
    const int orig = blockIdx.x;
    const int wgid = (orig & 7) * 100 + (orig >> 3);
    const int qt = wgid % 25, bh = wgid / 25;
    const int b = bh >> 3, head = bh & 7;
    const int tid = threadIdx.x, lane = tid & 63, wave = tid >> 6;
    const int qw = wave >> 2, kw = wave & 3;     // 2 q-groups x 4 token-quarters
    const int l15 = lane & 15, grp = lane >> 4;
    const int swz = (l15 & 7) << 4;

    __shared__ __align__(16) char smem[65536];
    char* bufA = smem;
    char* bufB = smem + 32768;

    const char* tiles = img + (size_t)bh * NTILE * TILE_BYTES;

    // Q fragments (B operand, col = l15 = q-row), straight from padded K image (1/8 baked in)
    f16x8 aq[2][2];
#pragma unroll
    for (int sub = 0; sub < 2; ++sub) {
        const int qrow = qt*64 + qw*32 + sub*16 + l15;      // <= 1599 < 1664: in padded image
        const char* qr = tiles + (size_t)(qrow >> 7) * TILE_BYTES + (size_t)(qrow & 127) * 128;
        aq[sub][0] = *(const f16x8*)(qr + ((grp*16) ^ swz));
        aq[sub][1] = *(const f16x8*)(qr + ((64 + grp*16) ^ swz));
    }

    f32x4 oacc[2][4];
    float lsum[2] = {0.f, 0.f};
#pragma unroll
    for (int s = 0; s < 2; ++s)
#pragma unroll
        for (int db = 0; db < 4; ++db) oacc[s][db] = f32x4{0.f, 0.f, 0.f, 0.f};

    // staging: linear byte copy, thread owns 4 x 16B chunks at stride 8KB (contiguous 1KB per wave-instr)
    uint4 st[4];
    const int soff = tid * 16;
    auto stage_load = [&](int t) {
        const char* g = tiles + (size_t)t * TILE_BYTES + soff;
#pragma unroll
        for (int c = 0; c < 4; ++c) st[c] = *(const uint4*)(g + c * 8192);
    };
    auto stage_write = [&](char* bufp) {
#pragma unroll
        for (int c = 0; c < 4; ++c) *(uint4*)(bufp + soff + c * 8192) = st[c];
    };

    stage_load(0); stage_write(bufA);
    __syncthreads();
    for (int p = 0; p < 6; ++p) {       // 13 tiles: 12 in the 2-unrolled loop + tail compute
        stage_load(2*p + 1);
        tile_compute<false>(bufA, kw, l15, grp, swz, aq, oacc, lsum);
        stage_write(bufB);
        __syncthreads();
        stage_load(2*p + 2);
        tile_compute<false>(bufB, kw, l15, grp, swz, aq, oacc, lsum);
        stage_write(bufA);
        __syncthreads();
    }
    tile_compute<true>(bufA, kw, l15, grp, swz, aq, oacc, lsum);   // tile 12 (zero-padded)

    // ---- combine 4 kw-quarters (kw 1..3 -> LDS, kw 0 adds), then store ----
    __syncthreads();                    // all tile reads done; smem reusable
    float* comb = (float*)smem;         // [6][64][35] f32
    if (kw != 0) {
        float* pp = comb + (size_t)((qw*3 + (kw-1))*64 + lane) * 35;
#pragma unroll
        for (int s = 0; s < 2; ++s)
#pragma unroll
            for (int db = 0; db < 4; ++db)
#pragma unroll
                for (int r = 0; r < 4; ++r) pp[s*16 + db*4 + r] = oacc[s][db][r];
        pp[32] = lsum[0]; pp[33] = lsum[1];
    }
    __syncthreads();
    if (kw == 0) {
#pragma unroll
        for (int s3 = 0; s3 < 3; ++s3) {
            const float* pp = comb + (size_t)((qw*3 + s3)*64 + lane) * 35;
#pragma unroll
            for (int s = 0; s < 2; ++s)
#pragma unroll
                for (int db = 0; db < 4; ++db)
#pragma unroll
                    for (int r = 0; r < 4; ++r) oacc[s][db][r] += pp[s*16 + db*4 + r];
            lsum[0] += pp[32]; lsum[1] += pp[33];
        }
        // sum the 4 grp-partials of each q-row
        lsum[0] += __shfl_xor(lsum[0], 16); lsum[0] += __shfl_xor(lsum[0], 32);
        lsum[1] += __shfl_xor(lsum[1], 16); lsum[1] += __shfl_xor(lsum[1], 32);

#pragma unroll
        for (int sub = 0; sub < 2; ++sub) {
            const int qrow = qt*64 + qw*32 + sub*16 + l15;
            if (qrow < NTOK) {
                const float inv = 1.0f / lsum[sub];
#pragma unroll
                for (int db = 0; db < 4; ++db)
#pragma unroll
                    for (int r = 0; r < 4; ++r) {
                        const int d = db*16 + 4*grp + r;     // O^T: row = d, col = q
                        out[((size_t)b * NCH + (size_t)d * NHEADS + head) * NTOK + qrow] = oacc[sub][db][r] * inv;
                    }
            }
        }
    }
}

extern "C" void kernel_launch(void* const* d_in, const int* in_sizes, int n_in,
                              void* d_out, int out_size, void* d_ws, size_t ws_size,
                              hipStream_t stream)
{
    const float* x = (const float*)d_in[0];
    float* out     = (float*)d_out;
    char* img      = (char*)d_ws;       // 32 * 13 * 32768 = 13.6 MB

    dim3 pgrid(32, NTILE);
    prep_kernel<<<pgrid, 256, 0, stream>>>(x, img);

    attn_fwd<<<800, 512, 0, stream>>>(img, out);
}

// Round 6
// 53.542 us; speedup vs baseline: 2.0567x; 2.0567x over previous
//
#include <hip/hip_runtime.h>

typedef _Float16 f16x8 __attribute__((ext_vector_type(8)));
typedef _Float16 f16x4 __attribute__((ext_vector_type(4)));
typedef float    f32x4 __attribute__((ext_vector_type(4)));

constexpr int NTOK   = 1568;       // T*H*W = 8*14*14
constexpr int NHEADS = 8;
constexpr int NCH    = 512;
constexpr int NC32   = 52;         // 32-token chunks, padded to 1664 tokens
constexpr float SK   = 0.15014030f; // 0.125*sqrt(log2 e): (q*SK)·(k*SK) = s*log2e/64 -> p = exp2(.)
constexpr size_t IMG_BH = (size_t)NC32 * 4096;   // 212992 B per (bh) per image

// ---- pre-pass: build fragment-major K and V images (every frag = contiguous 1KB, lane*16) ----
// K frag (c16 = tok/16, ks): slot(l15,grp,j) = x[tok=c16*16+l15][d=ks*32+8grp+j] * SK
// V frag (c32 = tok/32, db): slot(l15,grp,j) = x[tok=c32*32+16*(j>>2)+4grp+(j&3)][d=db*16+l15]
__global__ __launch_bounds__(256)
void prep_kernel(const float* __restrict__ x, char* __restrict__ Kimg, char* __restrict__ Vimg)
{
    const int bh = blockIdx.x, c32 = blockIdx.y;
    const int b = bh >> 3, h = bh & 7;
    const int t = threadIdx.x;
    const int f = t >> 6, l = t & 63, l15 = l & 15, grp = l >> 4;

    char* Kg = Kimg + (size_t)bh * IMG_BH + (size_t)(c32 * 4 + f) * 1024 + l * 16;
    char* Vg = Vimg + (size_t)bh * IMG_BH + (size_t)(c32 * 4 + f) * 1024 + l * 16;

    const int n0 = c32 * 32;
    if (n0 >= NTOK) {                       // pure padding chunk
        f16x8 z;
#pragma unroll
        for (int j = 0; j < 8; ++j) z[j] = (_Float16)0.f;
        *(f16x8*)Kg = z; *(f16x8*)Vg = z;
        return;
    }

    __shared__ _Float16 kbuf[32][72];       // [tok][d], scaled
    __shared__ _Float16 vbuf[64][40];       // [d][tok]

    const int tok = t & 31, dhi = t >> 5;   // coalesced: 8 x 128B segments per pass
#pragma unroll
    for (int p = 0; p < 8; ++p) {
        const int d = 8 * p + dhi;
        const float v = x[((size_t)b * NCH + d * NHEADS + h) * NTOK + n0 + tok];
        kbuf[tok][d] = (_Float16)(v * SK);
        vbuf[d][tok] = (_Float16)v;
    }
    __syncthreads();

    // K frag f: cb = f>>1 (16-tok half), ks = f&1
    *(f16x8*)Kg = *(const f16x8*)&kbuf[(f >> 1) * 16 + l15][(f & 1) * 32 + grp * 8];
    // V frag db = f: token quads {4grp..+3} and {16+4grp..+3}
    f16x4 va = *(const f16x4*)&vbuf[f * 16 + l15][4 * grp];
    f16x4 vb = *(const f16x4*)&vbuf[f * 16 + l15][16 + 4 * grp];
    f16x8 vv;
#pragma unroll
    for (int j = 0; j < 4; ++j) { vv[j] = va[j]; vv[4 + j] = vb[j]; }
    *(f16x8*)Vg = vv;
}

// ---- main attention: no LDS in hot loop, no barriers, L2-direct coalesced frag loads ----
__global__ __launch_bounds__(256, 3)
void attn_fwd(const char* __restrict__ Kimg, const char* __restrict__ Vimg,
              float* __restrict__ out)
{
    // XCD-aware bijective remap (800 = 8*100): 4 bh per XCD -> both images L2-resident
    const int orig = blockIdx.x;
    const int wgid = (orig & 7) * 100 + (orig >> 3);
    const int qt = wgid % 25, bh = wgid / 25;
    const int b = bh >> 3, head = bh & 7;
    const int t = threadIdx.x, kw = t >> 6, lane = t & 63;
    const int l15 = lane & 15, grp = lane >> 4;

    const char* Kb = Kimg + (size_t)bh * IMG_BH;
    const char* Vb = Vimg + (size_t)bh * IMG_BH;

    // Q fragments: B operand (col = l15 = q-row), from the padded K image (scale baked in)
    f16x8 aq[4][2];
#pragma unroll
    for (int sub = 0; sub < 4; ++sub)
#pragma unroll
        for (int ks = 0; ks < 2; ++ks)
            aq[sub][ks] = *(const f16x8*)(Kb + (size_t)((qt * 4 + sub) * 2 + ks) * 1024 + lane * 16);

    f32x4 oacc[4][4];
    float lsum[4];
#pragma unroll
    for (int s = 0; s < 4; ++s) {
        lsum[s] = 0.f;
#pragma unroll
        for (int db = 0; db < 4; ++db) oacc[s][db] = f32x4{0.f, 0.f, 0.f, 0.f};
    }

    // 49 valid chunks split 13/12/12/12 across the 4 kw waves
    const int start = (kw == 0) ? 0 : 13 + (kw - 1) * 12;
    const int nc    = (kw == 0) ? 13 : 12;
    const f32x4 z4 = {0.f, 0.f, 0.f, 0.f};

    for (int i = 0; i < nc; ++i) {
        const int c32 = start + i;
        const char* kbase = Kb + (size_t)c32 * 4096 + lane * 16;
        const char* vbase = Vb + (size_t)c32 * 4096 + lane * 16;

        f16x8 ka0 = *(const f16x8*)(kbase);
        f16x8 ka1 = *(const f16x8*)(kbase + 1024);
        f16x8 vf0 = *(const f16x8*)(vbase);
        f16x8 vf1 = *(const f16x8*)(vbase + 1024);

        f16x8 bp[4];
        // phase A: tokens c32*32 .. +15  (S^T rows 4grp+r, col l15 = q)
#pragma unroll
        for (int sub = 0; sub < 4; ++sub) {
            f32x4 s = __builtin_amdgcn_mfma_f32_16x16x32_f16(ka0, aq[sub][0], z4, 0, 0, 0);
            s = __builtin_amdgcn_mfma_f32_16x16x32_f16(ka1, aq[sub][1], s, 0, 0, 0);
            const float e0 = exp2f(s[0]), e1 = exp2f(s[1]), e2 = exp2f(s[2]), e3 = exp2f(s[3]);
            bp[sub][0] = (_Float16)e0; bp[sub][1] = (_Float16)e1;
            bp[sub][2] = (_Float16)e2; bp[sub][3] = (_Float16)e3;
            lsum[sub] += (e0 + e1) + (e2 + e3);
        }
        f16x8 kb0 = *(const f16x8*)(kbase + 2048);
        f16x8 kb1 = *(const f16x8*)(kbase + 3072);
        f16x8 vf2 = *(const f16x8*)(vbase + 2048);
        f16x8 vf3 = *(const f16x8*)(vbase + 3072);
        // phase B: tokens c32*32+16 .. +31
#pragma unroll
        for (int sub = 0; sub < 4; ++sub) {
            f32x4 s = __builtin_amdgcn_mfma_f32_16x16x32_f16(kb0, aq[sub][0], z4, 0, 0, 0);
            s = __builtin_amdgcn_mfma_f32_16x16x32_f16(kb1, aq[sub][1], s, 0, 0, 0);
            const float e0 = exp2f(s[0]), e1 = exp2f(s[1]), e2 = exp2f(s[2]), e3 = exp2f(s[3]);
            bp[sub][4] = (_Float16)e0; bp[sub][5] = (_Float16)e1;
            bp[sub][6] = (_Float16)e2; bp[sub][7] = (_Float16)e3;
            lsum[sub] += (e0 + e1) + (e2 + e3);
        }
        // PV: O^T += V^T P^T (A-frag token order == bp slot order by construction)
#pragma unroll
        for (int sub = 0; sub < 4; ++sub) {
            oacc[sub][0] = __builtin_amdgcn_mfma_f32_16x16x32_f16(vf0, bp[sub], oacc[sub][0], 0, 0, 0);
            oacc[sub][1] = __builtin_amdgcn_mfma_f32_16x16x32_f16(vf1, bp[sub], oacc[sub][1], 0, 0, 0);
            oacc[sub][2] = __builtin_amdgcn_mfma_f32_16x16x32_f16(vf2, bp[sub], oacc[sub][2], 0, 0, 0);
            oacc[sub][3] = __builtin_amdgcn_mfma_f32_16x16x32_f16(vf3, bp[sub], oacc[sub][3], 0, 0, 0);
        }
    }

    // ---- combine the 4 kw waves (sequential rounds, one small LDS buffer) ----
    __shared__ float comb[64][69];          // stride 69: gcd(69,32)=1, conflict-free
    for (int r = 1; r < 4; ++r) {
        if (kw == r) {
#pragma unroll
            for (int s = 0; s < 4; ++s) {
#pragma unroll
                for (int db = 0; db < 4; ++db)
#pragma unroll
                    for (int q = 0; q < 4; ++q) comb[lane][s * 16 + db * 4 + q] = oacc[s][db][q];
                comb[lane][64 + s] = lsum[s];
            }
        }
        __syncthreads();
        if (kw == 0) {
#pragma unroll
            for (int s = 0; s < 4; ++s) {
#pragma unroll
                for (int db = 0; db < 4; ++db)
#pragma unroll
                    for (int q = 0; q < 4; ++q) oacc[s][db][q] += comb[lane][s * 16 + db * 4 + q];
                lsum[s] += comb[lane][64 + s];
            }
        }
        __syncthreads();
    }

    if (kw == 0) {
#pragma unroll
        for (int s = 0; s < 4; ++s) {       // full row-denominator: reduce over grp groups
            lsum[s] += __shfl_xor(lsum[s], 16);
            lsum[s] += __shfl_xor(lsum[s], 32);
        }
#pragma unroll
        for (int sub = 0; sub < 4; ++sub) {
            const int qrow = qt * 64 + sub * 16 + l15;
            if (qrow < NTOK) {
                const float inv = 1.0f / lsum[sub];
#pragma unroll
                for (int db = 0; db < 4; ++db)
#pragma unroll
                    for (int q = 0; q < 4; ++q) {
                        const int d = db * 16 + 4 * grp + q;   // O^T: row=d, col=q
                        out[((size_t)b * NCH + (size_t)d * NHEADS + head) * NTOK + qrow] = oacc[sub][db][q] * inv;
                    }
            }
        }
    }
}

extern "C" void kernel_launch(void* const* d_in, const int* in_sizes, int n_in,
                              void* d_out, int out_size, void* d_ws, size_t ws_size,
                              hipStream_t stream)
{
    const float* x = (const float*)d_in[0];
    float* out     = (float*)d_out;

    char* Kimg = (char*)d_ws;                       // 32 * 208KB = 6.8 MB
    char* Vimg = (char*)d_ws + 32 * IMG_BH;         // + 6.8 MB

    dim3 pgrid(32, NC32);                           // 32 bh x 52 chunks
    prep_kernel<<<pgrid, 256, 0, stream>>>(x, Kimg, Vimg);

    attn_fwd<<<800, 256, 0, stream>>>(Kimg, Vimg, out);   // 25 q-tiles x 32 bh, XCD-remapped
}